// Round 1
// 387.188 us; speedup vs baseline: 1.0533x; 1.0533x over previous
//
#include <hip/hip_runtime.h>
#include <hip/hip_bf16.h>
#include <math.h>

// Problem: B=32, L=2048, E=512, Q=512, K=E+Q=1024, M=B*L=65536
// out = [applied (32*512 f32), weights (32*2048 f32)]
//
// v2 design (this round):
//  - convert_w_kernel: W -> bf16 once, with per-row byte-XOR swizzle baked in
//    (Wsw.byte[n][j] = bf16(W)[n].byte[j ^ ((n&7)<<4)]) so the GEMM can fill
//    LDS linearly with global_load_lds and still read conflict-free.
//  - scores_kernel: double-buffered LDS, A reg-staged 2-deep (f32->bf16 pack
//    deferred one step), B via global_load_lds(16B) from Wsw, XOR-swizzled
//    LDS on both tiles, setprio around MFMA. Epilogue unchanged
//    (tanh + v_w dot + shfl reduce + atomicAdd into scores).
//  - softmax_apply: same algorithm, 2x grid (32-row chunks), scores row
//    cached in regs across the max/sum passes.

typedef __attribute__((ext_vector_type(8))) short bf16x8;
typedef __attribute__((ext_vector_type(4))) float f32x4;

#define BDIM 32
#define LDIM 2048
#define EDIM 512
#define QDIM 512
#define KDIM 1024
#define MDIM (BDIM * LDIM)

#define BM 128
#define BN 128
#define BK 64
#define NSTEPS (KDIM / BK)   // 16

// pack two fp32 -> two bf16 (round-half-up == RNE except exact ties; ties have
// prob ~2^-16 on random data). 2 v_add + 1 v_perm per 2 elements.
__device__ __forceinline__ unsigned int pack2bf(float lo, float hi) {
    unsigned int a = __builtin_bit_cast(unsigned int, lo) + 0x8000u;
    unsigned int b = __builtin_bit_cast(unsigned int, hi) + 0x8000u;
    // dest bytes [0,1]=a[2,3], [2,3]=b[2,3]  (idx 0-3 = 2nd arg, 4-7 = 1st arg)
    return __builtin_amdgcn_perm(b, a, 0x07060302);
}

// ---------------------------------------------------------------------------
// W (512x1024 f32 row-major) -> bf16 with byte-XOR swizzle per row.
// Grid: 256 blocks x 256 thr; one 16B output block per thread.
__global__ __launch_bounds__(256) void convert_w_kernel(
    const float* __restrict__ W, unsigned short* __restrict__ Wsw)
{
    const int gid = blockIdx.x * 256 + threadIdx.x;   // 65536 = 512 rows * 128 blocks
    const int n  = gid >> 7;
    const int jb = (gid & 127) * 16;                  // output byte offset in 2048B row
    const int sb = jb ^ ((n & 7) << 4);               // source byte offset (XOR is 16B-granular)
    const float* src = W + (size_t)n * KDIM + (sb >> 2); // sb/4 floats... (sb bytes of bf16 = sb/2 cols)
    // careful: sb is a BF16-byte offset -> column = sb/2, float offset = sb/2
    src = W + (size_t)n * KDIM + (sb >> 1);
    const float4 a = *(const float4*)(src);
    const float4 c = *(const float4*)(src + 4);
    uint4 o;
    o.x = pack2bf(a.x, a.y); o.y = pack2bf(a.z, a.w);
    o.z = pack2bf(c.x, c.y); o.w = pack2bf(c.z, c.w);
    *(uint4*)((char*)Wsw + (size_t)n * 2048 + jb) = o;
}

// ---------------------------------------------------------------------------
// XOR-swizzled LDS fragment read: 16B at logical (row, colbyte) of a [128][64]
// bf16 tile stored with byte ^= (row&7)<<4. Conflict-free for the MFMA frag
// pattern (8 distinct 16B slots per 8 rows, 2-way alias beyond = free).
__device__ __forceinline__ bf16x8 lds_frag(const unsigned short* buf, int row, int cb) {
    return *(const bf16x8*)((const char*)buf + row * 128 + (cb ^ ((row & 7) << 4)));
}

__device__ __forceinline__ void load_a(const float* __restrict__ emb,
                                       const float* __restrict__ query,
                                       int m0, int kstep, int arow, int acol,
                                       float4 (&r)[8])
{
    const int k0 = kstep * BK;
    const float* asrc = (k0 < QDIM) ? query : emb;
    const int koff = (k0 < QDIM) ? k0 : (k0 - QDIM);
    #pragma unroll
    for (int p = 0; p < 8; p++)
        r[p] = *(const float4*)(asrc + (size_t)(m0 + p * 16 + arow) * 512 + koff + acol);
}

__device__ __forceinline__ void write_a(unsigned short* buf, int arow, int acolb,
                                        int axor, const float4 (&r)[8])
{
    #pragma unroll
    for (int p = 0; p < 8; p++) {
        uint2 pk;
        pk.x = pack2bf(r[p].x, r[p].y);
        pk.y = pack2bf(r[p].z, r[p].w);
        *(uint2*)((char*)buf + (p * 16 + arow) * 128 + (acolb ^ axor)) = pk;
    }
}

__device__ __forceinline__ void gll_b(const unsigned short* __restrict__ Wsw,
                                      unsigned short* buf, int n0, int kstep,
                                      int brow, int bcb, int wvoff)
{
    const size_t kb = (size_t)kstep * (BK * 2);
    #pragma unroll
    for (int p = 0; p < 4; p++) {
        const char* g = (const char*)Wsw + (size_t)(n0 + p * 32 + brow) * 2048 + kb + bcb;
        __builtin_amdgcn_global_load_lds(
            (const __attribute__((address_space(1))) void*)g,
            (__attribute__((address_space(3))) void*)((char*)buf + p * 4096 + wvoff),
            16, 0, 0);
    }
}

__device__ __forceinline__ void compute_step(const unsigned short* a_,
                                             const unsigned short* b_,
                                             int wm, int wn, int ln, int quad,
                                             f32x4 (&acc)[4][4])
{
    __builtin_amdgcn_s_setprio(1);
    #pragma unroll
    for (int ks = 0; ks < 2; ks++) {
        bf16x8 af[4], bf_[4];
        #pragma unroll
        for (int i = 0; i < 4; i++) af[i] = lds_frag(a_, wm + i * 16 + ln, ks * 64 + quad * 16);
        #pragma unroll
        for (int j = 0; j < 4; j++) bf_[j] = lds_frag(b_, wn + j * 16 + ln, ks * 64 + quad * 16);
        #pragma unroll
        for (int i = 0; i < 4; i++)
            #pragma unroll
            for (int j = 0; j < 4; j++)
                acc[i][j] = __builtin_amdgcn_mfma_f32_16x16x32_bf16(af[i], bf_[j], acc[i][j], 0, 0, 0);
    }
    __builtin_amdgcn_s_setprio(0);
}

__global__ __launch_bounds__(256, 2) void scores_kernel(
    const float* __restrict__ emb, const float* __restrict__ query,
    const unsigned short* __restrict__ Wsw, const float* __restrict__ b_attn,
    const float* __restrict__ v_w, float* __restrict__ scores)
{
    // dbuf: 4 x 16KB = 64 KB -> 2 blocks/CU (8 waves)
    __shared__ __align__(16) unsigned short As[2][BM * BK];
    __shared__ __align__(16) unsigned short Bs[2][BN * BK];

    const int tid = threadIdx.x;
    const int bid = blockIdx.x;
    // XCD-aware: give each XCD whole mtile groups so the 4 ntile-sharers of
    // one A-tile hit the same 4MB L2.
    const int xcd = bid & 7;
    const int slot = bid >> 3;
    const int mtile = xcd * 64 + (slot >> 2);
    const int ntile = slot & 3;
    const int m0 = mtile * BM;
    const int n0 = ntile * BN;

    const int lane = tid & 63;
    const int wv = tid >> 6;
    const int wm = (wv >> 1) * 64;
    const int wn = (wv & 1) * 64;
    const int quad = lane >> 4;
    const int ln = lane & 15;

    // A staging: 8 passes of 16 rows; thread -> row p*16+(tid>>4), 4 floats.
    const int arow  = tid >> 4;
    const int acol  = (tid & 15) * 4;     // float col
    const int acolb = acol * 2;           // byte col of 8B packed write
    const int axor  = (arow & 7) << 4;    // (row&7)<<4 is row-invariant here (16 | p*16)

    // B gll: issue p fills LDS bytes [p*4096 + tid*16]; row = p*32 + tid/8.
    const int brow = tid >> 3;
    const int bcb  = (tid & 7) * 16;
    const int wvoff = __builtin_amdgcn_readfirstlane((tid >> 6) << 10);

    f32x4 acc[4][4];
    #pragma unroll
    for (int i = 0; i < 4; i++)
        #pragma unroll
        for (int j = 0; j < 4; j++)
            acc[i][j] = (f32x4){0.f, 0.f, 0.f, 0.f};

    float4 ra[8], rb[8];

    // prologue: buf0 <- step 0; prefetch step 1 into rb
    load_a(emb, query, m0, 0, arow, acol, ra);
    write_a(&As[0][0], arow, acolb, axor, ra);   // compiler inserts the vmcnt wait
    gll_b(Wsw, &Bs[0][0], n0, 0, brow, bcb, wvoff);
    load_a(emb, query, m0, 1, arow, acol, rb);
    __syncthreads();

    for (int t = 0; t < NSTEPS; t += 2) {
        // even step t (cur=0): pack rb = data t+1, prefetch ra = data t+2
        if (t < NSTEPS - 2) load_a(emb, query, m0, t + 2, arow, acol, ra);
        write_a(&As[1][0], arow, acolb, axor, rb);
        gll_b(Wsw, &Bs[1][0], n0, t + 1, brow, bcb, wvoff);
        compute_step(&As[0][0], &Bs[0][0], wm, wn, ln, quad, acc);
        __syncthreads();

        // odd step t+1 (cur=1): pack ra = data t+2, prefetch rb = data t+3
        if (t + 1 < NSTEPS - 1) {
            if (t + 1 < NSTEPS - 2) load_a(emb, query, m0, t + 3, arow, acol, rb);
            write_a(&As[0][0], arow, acolb, axor, ra);
            gll_b(Wsw, &Bs[0][0], n0, t + 2, brow, bcb, wvoff);
        }
        compute_step(&As[1][0], &Bs[1][0], wm, wn, ln, quad, acc);
        __syncthreads();
    }

    // ---- fused epilogue: sum_n tanh(x + b[n]) * v_w[n], reduce over 16 cols ----
    float bj[4], vj[4];
    #pragma unroll
    for (int j = 0; j < 4; j++) {
        const int n = n0 + wn + j * 16 + ln;
        bj[j] = b_attn[n];
        vj[j] = v_w[n];
    }
    #pragma unroll
    for (int i = 0; i < 4; i++) {
        #pragma unroll
        for (int r = 0; r < 4; r++) {
            float s = 0.f;
            #pragma unroll
            for (int j = 0; j < 4; j++)
                s += tanhf(acc[i][j][r] + bj[j]) * vj[j];
            #pragma unroll
            for (int off = 1; off < 16; off <<= 1)
                s += __shfl_xor(s, off, 64);
            if (ln == 0)
                atomicAdd(&scores[m0 + wm + i * 16 + quad * 4 + r], s);
        }
    }
}

// ---------------------------------------------------------------------------
__global__ __launch_bounds__(256) void softmax_apply_kernel(
    const float* __restrict__ emb, const float* __restrict__ scores,
    float* __restrict__ out_applied, float* __restrict__ out_weights)
{
    const int b = blockIdx.x >> 6;      // 64 L-chunks of 32 rows
    const int chunk = blockIdx.x & 63;
    const int l0 = chunk * 32;
    const int tid = threadIdx.x;
    const float* srow = scores + (size_t)b * LDIM;

    __shared__ float red[4];
    __shared__ float wls[32];
    __shared__ float partial[512];

    // redundant-but-deterministic softmax stats over full row (8 KB, L2-hot);
    // row cached in regs across the max and sum passes.
    float sv[8];
    #pragma unroll
    for (int t = 0; t < 8; t++) sv[t] = srow[tid + t * 256];

    float mx = sv[0];
    #pragma unroll
    for (int t = 1; t < 8; t++) mx = fmaxf(mx, sv[t]);
    #pragma unroll
    for (int off = 1; off < 64; off <<= 1) mx = fmaxf(mx, __shfl_xor(mx, off, 64));
    if ((tid & 63) == 0) red[tid >> 6] = mx;
    __syncthreads();
    mx = fmaxf(fmaxf(red[0], red[1]), fmaxf(red[2], red[3]));

    float sm = 0.f;
    #pragma unroll
    for (int t = 0; t < 8; t++) sm += expf(sv[t] - mx);
    #pragma unroll
    for (int off = 1; off < 64; off <<= 1) sm += __shfl_xor(sm, off, 64);
    __syncthreads();
    if ((tid & 63) == 0) red[tid >> 6] = sm;
    __syncthreads();
    sm = red[0] + red[1] + red[2] + red[3];
    const float inv = 1.f / sm;

    if (tid < 32) {
        const float w = expf(srow[l0 + tid] - mx) * inv;
        wls[tid] = w;
        out_weights[(size_t)b * LDIM + l0 + tid] = w;
    }
    __syncthreads();

    // weighted sum over 32 rows: two row-halves each do 16 strided rows with
    // float4 loads, then LDS cross-half reduce + atomics.
    const int half = tid >> 7;          // wave-uniform
    const int cg = tid & 127;           // column group of 4 floats
    float4 acc = {0.f, 0.f, 0.f, 0.f};
    const float* ebase = emb + ((size_t)b * LDIM + l0 + half) * EDIM + cg * 4;
    #pragma unroll
    for (int i = 0; i < 16; i++) {
        const float4 v = *(const float4*)(ebase + (size_t)2 * i * EDIM);
        const float w = wls[half + 2 * i];
        acc.x += w * v.x;
        acc.y += w * v.y;
        acc.z += w * v.z;
        acc.w += w * v.w;
    }
    if (half == 1) *(float4*)&partial[cg * 4] = acc;
    __syncthreads();
    if (half == 0) {
        const float4 p = *(const float4*)&partial[cg * 4];
        float* dst = out_applied + (size_t)b * EDIM + cg * 4;
        atomicAdd(dst + 0, acc.x + p.x);
        atomicAdd(dst + 1, acc.y + p.y);
        atomicAdd(dst + 2, acc.z + p.z);
        atomicAdd(dst + 3, acc.w + p.w);
    }
}

extern "C" void kernel_launch(void* const* d_in, const int* in_sizes, int n_in,
                              void* d_out, int out_size, void* d_ws, size_t ws_size,
                              hipStream_t stream) {
    const float* emb    = (const float*)d_in[0];
    const float* query  = (const float*)d_in[1];
    const float* W      = (const float*)d_in[2];
    const float* b_attn = (const float*)d_in[3];
    const float* v_w    = (const float*)d_in[4];

    float* out     = (float*)d_out;
    float* applied = out;                 // 32*512 floats
    float* weights = out + BDIM * EDIM;   // 32*2048 floats

    float* scores  = (float*)d_ws;                                          // 256 KB
    unsigned short* Wsw = (unsigned short*)((char*)d_ws + (size_t)MDIM * 4); // 1 MB swizzled bf16 W

    hipMemsetAsync(scores, 0, (size_t)MDIM * sizeof(float), stream);
    hipMemsetAsync(applied, 0, (size_t)BDIM * EDIM * sizeof(float), stream);

    convert_w_kernel<<<256, 256, 0, stream>>>(W, Wsw);

    // grid = (M/BM) * (N/BN) = 512 * 4 = 2048 blocks
    scores_kernel<<<2048, 256, 0, stream>>>(emb, query, Wsw, b_attn, v_w, scores);

    // grid = B * 64 chunks = 2048 blocks
    softmax_apply_kernel<<<2048, 256, 0, stream>>>(emb, scores, applied, weights);
}